// Round 1
// baseline (158.420 us; speedup 1.0000x reference)
//
#include <hip/hip_runtime.h>

typedef unsigned int  u32;
typedef unsigned short u16;

typedef __bf16 bf16x8 __attribute__((ext_vector_type(8)));
typedef float  floatx4 __attribute__((ext_vector_type(4)));

#define N_ROWS 256
#define IN_F   8192
#define OUT_F  8320
#define JDIM   128
#define KDIM   16
#define JK     2048

#define BN     64
#define BK     32
#define KCHUNK 512

typedef const __attribute__((address_space(1))) u32 gu32;
typedef __attribute__((address_space(3))) u32 su32;

__device__ __forceinline__ u16 f2bf(float f) {
    u32 u = __float_as_uint(f);
    u32 r = u + 0x7fffu + ((u >> 16) & 1u);
    return (u16)(r >> 16);
}

// Kernel A: copy X into out[:, :8192], convert X->bf16 into ws, zero feats + diversity region.
__global__ __launch_bounds__(256) void prep_kernel(const float* __restrict__ X,
                                                   float* __restrict__ out,
                                                   u16* __restrict__ Xb,
                                                   float* __restrict__ feats)
{
    int t = blockIdx.x * 256 + threadIdx.x;      // 0..524287, one float4 each
    float4 v = reinterpret_cast<const float4*>(X)[t];
    int row = t >> 11;                           // 2048 float4 per row
    int c4  = t & 2047;
    reinterpret_cast<float4*>(out + (size_t)row * OUT_F)[c4] = v;
    ushort4 b;
    b.x = f2bf(v.x); b.y = f2bf(v.y); b.z = f2bf(v.z); b.w = f2bf(v.w);
    reinterpret_cast<ushort4*>(Xb)[t] = b;
    if (t < 131072) reinterpret_cast<float4*>(feats)[t] = make_float4(0.f, 0.f, 0.f, 0.f);
    if (t < 8192) {
        int r2 = t >> 5, j4 = t & 31;            // 32 float4 per row of the 128-wide diversity block
        reinterpret_cast<float4*>(out + (size_t)r2 * OUT_F + IN_F)[j4] = make_float4(0.f, 0.f, 0.f, 0.f);
    }
}

// Kernel B: feats(+)= Xb[256x8192]_bf16 * W[8192x2048]_fp32(cvt bf16), split-K atomics.
// Block tile: 256 rows x 64 cols, BK=32. Grid (2048/64=32, 8192/512=16) = 512 blocks.
__global__ __launch_bounds__(256) void gemm_kernel(const u16* __restrict__ Xb,
                                                   const float* __restrict__ W,
                                                   float* __restrict__ feats)
{
    // X tile: [row 0..255][k-quarter qs 0..3][8 bf16] = 64 B/row, quarters XOR-swizzled
    __shared__ u16 xs[N_ROWS * BK];        // 16 KB
    // W tile transposed: [col 0..63][k 0..31] bf16, padded row stride 40 elems (80 B)
    __shared__ u16 wt[BN * 40];            // 5 KB

    const int tid  = threadIdx.x;
    const int lane = tid & 63;
    const int wave = tid >> 6;
    const int c0   = blockIdx.x * BN;
    const int kbase = blockIdx.y * KCHUNK;

    floatx4 acc[4][4] = {};                // [row-tile][col-tile]

    const int xrow_in_grp = lane >> 2;     // 0..15
    const int xqs         = lane & 3;      // LDS quarter slot this lane fills
    const int wc  = tid >> 2;              // 0..63 (col)
    const int wkp = tid & 3;               // 0..3

    for (int kk = 0; kk < KCHUNK; kk += BK) {
        const int k0 = kbase + kk;
        __syncthreads();                   // previous iteration's LDS reads done

        // --- stage X: each wave stages its own 64 rows via global_load_lds (16B/lane) ---
        #pragma unroll
        for (int g = 0; g < 4; ++g) {
            int row = wave * 64 + g * 16 + xrow_in_grp;          // LDS+global row
            int qg  = xqs ^ ((row >> 1) & 3);                    // swizzle: slot qs holds global quarter qg
            const u16* gp = Xb + (size_t)row * IN_F + k0 + qg * 8;
            u32* lp = (u32*)&xs[(wave * 64 + g * 16) * BK];      // wave-uniform base; lane i -> +i*16B
            __builtin_amdgcn_global_load_lds((gu32*)gp, (su32*)lp, 16, 0, 0);
        }

        // --- stage W: fp32 load (64B chunks per k-row), cvt bf16, transposed pair-packed write ---
        #pragma unroll
        for (int r = 0; r < 4; ++r) {
            int k = r * 8 + wkp * 2;
            const float* wp = W + (size_t)(k0 + k) * JK + c0 + wc;
            float w0 = wp[0];
            float w1 = wp[JK];
            u32 pk = (u32)f2bf(w0) | ((u32)f2bf(w1) << 16);
            *(u32*)&wt[wc * 40 + k] = pk;                        // byte addr wc*80 + k*2
        }
        __syncthreads();

        // --- fragments + MFMA ---
        const int q    = lane >> 4;            // k-quad
        const int mrow = lane & 15;            // A row / B col within tile
        const int qsw  = q ^ ((mrow >> 1) & 3);
        bf16x8 a[4], b[4];
        #pragma unroll
        for (int rt = 0; rt < 4; ++rt) {
            int row = wave * 64 + rt * 16 + mrow;
            a[rt] = *reinterpret_cast<const bf16x8*>(&xs[row * BK + qsw * 8]);
        }
        #pragma unroll
        for (int ct = 0; ct < 4; ++ct) {
            int col = ct * 16 + mrow;
            b[ct] = *reinterpret_cast<const bf16x8*>(&wt[col * 40 + q * 8]);
        }
        #pragma unroll
        for (int rt = 0; rt < 4; ++rt)
            #pragma unroll
            for (int ct = 0; ct < 4; ++ct)
                acc[rt][ct] = __builtin_amdgcn_mfma_f32_16x16x32_bf16(a[rt], b[ct], acc[rt][ct], 0, 0, 0);
    }

    // --- epilogue: split-K accumulate. D mapping: col=lane&15, row=(lane>>4)*4+reg ---
    const int q = lane >> 4;
    const int col_l = lane & 15;
    #pragma unroll
    for (int rt = 0; rt < 4; ++rt)
        #pragma unroll
        for (int ct = 0; ct < 4; ++ct)
            #pragma unroll
            for (int r = 0; r < 4; ++r) {
                int row = wave * 64 + rt * 16 + q * 4 + r;
                int col = c0 + ct * 16 + col_l;
                atomicAdd(&feats[(size_t)row * JK + col], acc[rt][ct][r]);
            }
}

// Kernel C: diversity[n,j] = sum_m exp(-sum_k |feats[n,j,k]-feats[m,j,k]|), m-chunked, atomicAdd to out.
__global__ __launch_bounds__(256) void pairwise_kernel(const float* __restrict__ feats,
                                                       float* __restrict__ out)
{
    const int j = blockIdx.x;              // 0..127
    const int mq = blockIdx.y;             // 0..3 -> m chunk of 64
    const int n = threadIdx.x;

    __shared__ float F[N_ROWS * KDIM];     // 16 KB
    const float* fr = feats + (size_t)n * JK + j * KDIM;
    float4 v0 = ((const float4*)fr)[0];
    float4 v1 = ((const float4*)fr)[1];
    float4 v2 = ((const float4*)fr)[2];
    float4 v3 = ((const float4*)fr)[3];
    float4* Fp = (float4*)&F[n * KDIM];
    Fp[0] = v0; Fp[1] = v1; Fp[2] = v2; Fp[3] = v3;
    __syncthreads();

    float f[16] = { v0.x, v0.y, v0.z, v0.w, v1.x, v1.y, v1.z, v1.w,
                    v2.x, v2.y, v2.z, v2.w, v3.x, v3.y, v3.z, v3.w };
    float accum = 0.f;
    const int m0 = mq * 64;
    for (int m = 0; m < 64; ++m) {
        const float* Fm = &F[(m0 + m) * KDIM];   // wave-uniform -> LDS broadcast
        float l1 = 0.f;
        #pragma unroll
        for (int k = 0; k < 16; ++k) l1 += fabsf(f[k] - Fm[k]);
        accum += exp2f(-1.4426950408889634f * l1);
    }
    atomicAdd(&out[(size_t)n * OUT_F + IN_F + j], accum);
}

extern "C" void kernel_launch(void* const* d_in, const int* in_sizes, int n_in,
                              void* d_out, int out_size, void* d_ws, size_t ws_size,
                              hipStream_t stream)
{
    const float* X = (const float*)d_in[0];   // [256, 8192] fp32
    const float* T = (const float*)d_in[1];   // [8192, 128, 16] fp32 = [8192, 2048]
    float* out = (float*)d_out;               // [256, 8320] fp32

    float* feats = (float*)d_ws;                           // 2 MB: [256, 2048] fp32
    u16*   Xb    = (u16*)((char*)d_ws + 2u * 1024 * 1024); // 4 MB: [256, 8192] bf16

    prep_kernel<<<2048, 256, 0, stream>>>(X, out, Xb, feats);
    gemm_kernel<<<dim3(JK / BN, IN_F / KCHUNK), 256, 0, stream>>>(Xb, T, feats);
    pairwise_kernel<<<dim3(JDIM, 4), 256, 0, stream>>>(feats, out);
}

// Round 2
// 148.410 us; speedup vs baseline: 1.0674x; 1.0674x over previous
//
#include <hip/hip_runtime.h>

typedef unsigned int  u32;
typedef unsigned short u16;

typedef __bf16 bf16x8 __attribute__((ext_vector_type(8)));
typedef float  floatx4 __attribute__((ext_vector_type(4)));

#define N_ROWS 256
#define IN_F   8192
#define OUT_F  8320
#define JDIM   128
#define KDIM   16
#define JK     2048

#define BM     128
#define BN     64
#define BK     64

typedef const __attribute__((address_space(1))) u32 gu32;
typedef __attribute__((address_space(3))) u32 su32;

__device__ __forceinline__ u16 f2bf(float f) {
    u32 u = __float_as_uint(f);
    return (u16)((u + 0x7fffu + ((u >> 16) & 1u)) >> 16);
}
__device__ __forceinline__ float bf2f(u16 h) { return __uint_as_float(((u32)h) << 16); }

// Kernel A: copy X into out[:, :8192], convert X->bf16 into Xb, zero diversity region of out.
__global__ __launch_bounds__(256) void prep_kernel(const float* __restrict__ X,
                                                   float* __restrict__ out,
                                                   u16* __restrict__ Xb)
{
    int t = blockIdx.x * 256 + threadIdx.x;      // 0..524287, one float4 each
    float4 v = reinterpret_cast<const float4*>(X)[t];
    int row = t >> 11;                           // 2048 float4 per row
    int c4  = t & 2047;
    reinterpret_cast<float4*>(out + (size_t)row * OUT_F)[c4] = v;
    ushort4 b;
    b.x = f2bf(v.x); b.y = f2bf(v.y); b.z = f2bf(v.z); b.w = f2bf(v.w);
    reinterpret_cast<ushort4*>(Xb)[t] = b;
    if (t < 8192) {
        int r2 = t >> 5, j4 = t & 31;            // 32 float4 per 128-wide diversity row
        reinterpret_cast<float4*>(out + (size_t)r2 * OUT_F + IN_F)[j4] = make_float4(0.f, 0.f, 0.f, 0.f);
    }
}

// Kernel B: slab[s] = Xb[rows, kslab] * W[kslab, cols] in bf16, NO atomics.
// Tile: 128 rows x 64 cols x BK=64. Grid (32 col-blocks, 2 row-blocks, S k-slabs).
// LDS layouts XOR-swizzled in 16B chunks: slot = chunk ^ (row&7) -> 2-way banks (free),
// and matches global_load_lds's forced base+lane*16 destination.
__global__ __launch_bounds__(256, 4) void gemm_kernel(const u16* __restrict__ Xb,
                                                      const float* __restrict__ W,
                                                      u16* __restrict__ slabs,
                                                      int kchunk)
{
    __shared__ u16 xs[BM * BK];     // [row][slot*8], 16 KB
    __shared__ u16 wt[BN * BK];     // [col][slot*8], 8 KB

    const int tid  = threadIdx.x;
    const int lane = tid & 63;
    const int wave = tid >> 6;
    const int c0   = blockIdx.x * BN;
    const int row0 = blockIdx.y * BM;
    const int s    = blockIdx.z;
    const int k0base = s * kchunk;

    floatx4 acc[2][4] = {};

    const int xrl = lane >> 3;            // row within 8-row staging group
    const int xgc = (lane & 7) ^ xrl;     // global 16B chunk this lane fetches (swizzle)
    const int wcol = lane;                // W staging: col 0..63
    const int wkh  = wave;                // W staging: k-quarter

    const int iters = kchunk >> 6;
    for (int it = 0; it < iters; ++it) {
        const int k0 = k0base + it * BK;
        __syncthreads();

        // --- stage X: 128 rows x 64 k bf16 via global_load_lds (16B/lane) ---
        #pragma unroll
        for (int g = 0; g < 4; ++g) {
            int rbase = wave * 32 + g * 8;
            const u16* gp = Xb + (size_t)(row0 + rbase + xrl) * IN_F + k0 + xgc * 8;
            u32* lp = (u32*)&xs[rbase * BK];          // wave-uniform base; HW adds lane*16B
            __builtin_amdgcn_global_load_lds((gu32*)gp, (su32*)lp, 16, 0, 0);
        }

        // --- stage W: 64 k x 64 cols fp32 -> bf16, [col][k] swizzled, b128 LDS writes ---
        u32 pk[2][4];
        #pragma unroll
        for (int cc = 0; cc < 2; ++cc) {
            int chunk = wkh * 2 + cc;                 // 8-k chunk index 0..7
            const float* wp = W + (size_t)(k0 + chunk * 8) * JK + c0 + wcol;
            #pragma unroll
            for (int p = 0; p < 4; ++p) {
                float w0 = wp[(size_t)(2 * p) * JK];
                float w1 = wp[(size_t)(2 * p + 1) * JK];
                pk[cc][p] = (u32)f2bf(w0) | ((u32)f2bf(w1) << 16);
            }
        }
        #pragma unroll
        for (int cc = 0; cc < 2; ++cc) {
            int chunk = wkh * 2 + cc;
            int slot  = chunk ^ (wcol & 7);
            *(uint4*)&wt[wcol * BK + slot * 8] = *(uint4*)pk[cc];
        }
        __syncthreads();

        // --- fragments + MFMA: wave covers rows wave*32..+31 (2 tiles) x all 64 cols ---
        const int mrow = lane & 15;
        const int q    = lane >> 4;
        #pragma unroll
        for (int h = 0; h < 2; ++h) {
            bf16x8 a[2], b[4];
            #pragma unroll
            for (int rt = 0; rt < 2; ++rt) {
                int rl   = wave * 32 + rt * 16 + mrow;
                int slot = (h * 4 + q) ^ (rl & 7);
                a[rt] = *reinterpret_cast<const bf16x8*>(&xs[rl * BK + slot * 8]);
            }
            #pragma unroll
            for (int ct = 0; ct < 4; ++ct) {
                int col  = ct * 16 + mrow;
                int slot = (h * 4 + q) ^ (col & 7);
                b[ct] = *reinterpret_cast<const bf16x8*>(&wt[col * BK + slot * 8]);
            }
            #pragma unroll
            for (int rt = 0; rt < 2; ++rt)
                #pragma unroll
                for (int ct = 0; ct < 4; ++ct)
                    acc[rt][ct] = __builtin_amdgcn_mfma_f32_16x16x32_bf16(a[rt], b[ct], acc[rt][ct], 0, 0, 0);
        }
    }

    // --- epilogue: plain bf16 stores to this slab. D: col=lane&15, row=(lane>>4)*4+reg ---
    const int qe = lane >> 4;
    const int cl = lane & 15;
    u16* sp = slabs + (size_t)s * N_ROWS * JK;
    #pragma unroll
    for (int rt = 0; rt < 2; ++rt)
        #pragma unroll
        for (int ct = 0; ct < 4; ++ct)
            #pragma unroll
            for (int r = 0; r < 4; ++r) {
                int row = row0 + wave * 32 + rt * 16 + qe * 4 + r;
                int col = c0 + ct * 16 + cl;
                sp[(size_t)row * JK + col] = f2bf(acc[rt][ct][r]);
            }
}

// Kernel C: feats[n,jk] = sum_s slab[s][n,jk] (bf16 -> fp32).
__global__ __launch_bounds__(256) void reduce_kernel(const u16* __restrict__ slabs,
                                                     float* __restrict__ feats, int S)
{
    int t = blockIdx.x * 256 + threadIdx.x;      // 65536 threads x 8 elems
    float acc[8] = {};
    for (int s = 0; s < S; ++s) {
        uint4 v = *(const uint4*)(slabs + (size_t)s * N_ROWS * JK + (size_t)t * 8);
        const u16* h = (const u16*)&v;
        #pragma unroll
        for (int e = 0; e < 8; ++e) acc[e] += bf2f(h[e]);
    }
    float4* fp = (float4*)(feats + (size_t)t * 8);
    fp[0] = make_float4(acc[0], acc[1], acc[2], acc[3]);
    fp[1] = make_float4(acc[4], acc[5], acc[6], acc[7]);
}

// Kernel D: diversity[n,j] = sum_m exp(-sum_k |feats[n,j,k]-feats[m,j,k]|), m-chunked.
__global__ __launch_bounds__(256) void pairwise_kernel(const float* __restrict__ feats,
                                                       float* __restrict__ out)
{
    const int j = blockIdx.x;              // 0..127
    const int mq = blockIdx.y;             // 0..3 -> m chunk of 64
    const int n = threadIdx.x;

    __shared__ float F[N_ROWS * KDIM];     // 16 KB
    const float* fr = feats + (size_t)n * JK + j * KDIM;
    float4 v0 = ((const float4*)fr)[0];
    float4 v1 = ((const float4*)fr)[1];
    float4 v2 = ((const float4*)fr)[2];
    float4 v3 = ((const float4*)fr)[3];
    float4* Fp = (float4*)&F[n * KDIM];
    Fp[0] = v0; Fp[1] = v1; Fp[2] = v2; Fp[3] = v3;
    __syncthreads();

    float f[16] = { v0.x, v0.y, v0.z, v0.w, v1.x, v1.y, v1.z, v1.w,
                    v2.x, v2.y, v2.z, v2.w, v3.x, v3.y, v3.z, v3.w };
    float accum = 0.f;
    const int m0 = mq * 64;
    for (int m = 0; m < 64; ++m) {
        const float* Fm = &F[(m0 + m) * KDIM];   // wave-uniform -> LDS broadcast
        float l1 = 0.f;
        #pragma unroll
        for (int k = 0; k < 16; ++k) l1 += fabsf(f[k] - Fm[k]);
        accum += exp2f(-1.4426950408889634f * l1);
    }
    atomicAdd(&out[(size_t)n * OUT_F + IN_F + j], accum);
}

extern "C" void kernel_launch(void* const* d_in, const int* in_sizes, int n_in,
                              void* d_out, int out_size, void* d_ws, size_t ws_size,
                              hipStream_t stream)
{
    const float* X = (const float*)d_in[0];   // [256, 8192] fp32
    const float* T = (const float*)d_in[1];   // [8192, 128, 16] fp32 = [8192, 2048]
    float* out = (float*)d_out;               // [256, 8320] fp32

    float* feats = (float*)d_ws;                            // 2 MB fp32 [256,2048]
    u16*   Xb    = (u16*)((char*)d_ws + (2u << 20));        // 4 MB bf16 [256,8192]
    u16*   slabs = (u16*)((char*)d_ws + (6u << 20));        // S MB bf16 [S,256,2048]

    int S = 16;                                             // split-K factor
    if (ws_size < (6u << 20) + (size_t)16 * N_ROWS * JK * 2) S = 8;
    if (ws_size < (6u << 20) + (size_t)8  * N_ROWS * JK * 2) S = 4;
    int kchunk = IN_F / S;

    prep_kernel<<<2048, 256, 0, stream>>>(X, out, Xb);
    gemm_kernel<<<dim3(JK / BN, N_ROWS / BM, S), 256, 0, stream>>>(Xb, T, slabs, kchunk);
    reduce_kernel<<<256, 256, 0, stream>>>(slabs, feats, S);
    pairwise_kernel<<<dim3(JDIM, 4), 256, 0, stream>>>(feats, out);
}

// Round 3
// 139.023 us; speedup vs baseline: 1.1395x; 1.0675x over previous
//
#include <hip/hip_runtime.h>

typedef unsigned int  u32;
typedef unsigned short u16;

typedef __bf16 bf16x8 __attribute__((ext_vector_type(8)));
typedef float  floatx4 __attribute__((ext_vector_type(4)));

#define N_ROWS 256
#define IN_F   8192
#define OUT_F  8320
#define JDIM   128
#define KDIM   16
#define JK     2048

#define BM     256
#define BN     64
#define BK     64
#define WSTRIDE 72   // u16 units; 144 B = 9*16 -> b128-aligned, 2-way banks (free)

typedef const __attribute__((address_space(1))) u32 gu32;
typedef __attribute__((address_space(3))) u32 su32;

__device__ __forceinline__ u16 f2bf(float f) {
    u32 u = __float_as_uint(f);
    return (u16)((u + 0x7fffu + ((u >> 16) & 1u)) >> 16);
}
__device__ __forceinline__ float bf2f(u16 h) { return __uint_as_float(((u32)h) << 16); }

// Kernel A: copy X into out[:, :8192], convert X->bf16 into Xb, zero diversity region of out.
__global__ __launch_bounds__(256) void prep_kernel(const float* __restrict__ X,
                                                   float* __restrict__ out,
                                                   u16* __restrict__ Xb)
{
    int t = blockIdx.x * 256 + threadIdx.x;      // 0..524287, one float4 each
    float4 v = reinterpret_cast<const float4*>(X)[t];
    int row = t >> 11;                           // 2048 float4 per row
    int c4  = t & 2047;
    reinterpret_cast<float4*>(out + (size_t)row * OUT_F)[c4] = v;
    ushort4 b;
    b.x = f2bf(v.x); b.y = f2bf(v.y); b.z = f2bf(v.z); b.w = f2bf(v.w);
    reinterpret_cast<ushort4*>(Xb)[t] = b;
    if (t < 8192) {
        int r2 = t >> 5, j4 = t & 31;            // 32 float4 per 128-wide diversity row
        reinterpret_cast<float4*>(out + (size_t)r2 * OUT_F + IN_F)[j4] = make_float4(0.f, 0.f, 0.f, 0.f);
    }
}

// Kernel B: slab[s] = Xb[256 rows, kslab] * W[kslab, 64 cols] bf16 MFMA, no atomics.
// BM=256 (full M): W is fetched once. Grid (2048/64 = 32 col-blocks, S slabs).
// W staged via 4x dwordx4/thread (wide coalesced), bf16-packed to [col][k] LDS;
// next iter's W register-prefetched AFTER the 2nd barrier so HBM latency overlaps MFMA.
__global__ __launch_bounds__(256) void gemm_kernel(const u16* __restrict__ Xb,
                                                   const float* __restrict__ W,
                                                   u16* __restrict__ slabs,
                                                   int kchunk)
{
    __shared__ u16 xs[BM * BK];         // 32 KB, [row][slot*8] XOR-swizzled 16B chunks
    __shared__ u16 wt[BN * WSTRIDE];    // 9 KB,  [col][k] padded

    const int tid  = threadIdx.x;
    const int lane = tid & 63;
    const int wave = tid >> 6;
    const int c0   = blockIdx.x * BN;
    const int s    = blockIdx.y;
    const int k0base = s * kchunk;

    floatx4 acc[4][4] = {};             // wave owns rows wave*64..+63, all 64 cols

    const int xrl = lane >> 3;          // row within 8-row staging group
    const int xgc = (lane & 7) ^ xrl;   // global 16B chunk fetched into slot lane&7
    const int wk  = (tid >> 4) << 2;    // W staging k-quad base: 0,4,...,60
    const int wc  = (tid & 15) << 2;    // W staging col group: 0,4,...,60

    const float* wptr = W + (size_t)(k0base + wk) * JK + c0 + wc;

    // prologue: prefetch iter-0 W tile into registers (4x dwordx4)
    float4 wreg[4];
    #pragma unroll
    for (int r = 0; r < 4; ++r)
        wreg[r] = *(const float4*)(wptr + (size_t)r * JK);

    const int iters = kchunk >> 6;
    for (int it = 0; it < iters; ++it) {
        const int k0 = k0base + it * BK;
        __syncthreads();                // readers of previous tile done

        // --- stage X: each wave its own 64 rows, 8 rows/instr via global_load_lds 16B ---
        #pragma unroll
        for (int g = 0; g < 8; ++g) {
            int rbase = wave * 64 + g * 8;
            const u16* gp = Xb + (size_t)(rbase + xrl) * IN_F + k0 + xgc * 8;
            u32* lp = (u32*)&xs[rbase * BK];          // wave-uniform base; HW adds lane*16B
            __builtin_amdgcn_global_load_lds((gu32*)gp, (su32*)lp, 16, 0, 0);
        }

        // --- W: pack prefetched regs (4 cols x 4 k) -> bf16 [col][k], b64 writes ---
        {
            const float* wr = (const float*)wreg;
            #pragma unroll
            for (int i = 0; i < 4; ++i) {
                u32 lo = (u32)f2bf(wr[0 * 4 + i]) | ((u32)f2bf(wr[1 * 4 + i]) << 16);
                u32 hi = (u32)f2bf(wr[2 * 4 + i]) | ((u32)f2bf(wr[3 * 4 + i]) << 16);
                uint2 v; v.x = lo; v.y = hi;
                *(uint2*)&wt[(wc + i) * WSTRIDE + wk] = v;
            }
        }
        __syncthreads();

        // --- prefetch next iter's W tile; stays in flight across the MFMA section ---
        if (it + 1 < iters) {
            const float* wn = wptr + (size_t)(it + 1) * BK * JK;
            #pragma unroll
            for (int r = 0; r < 4; ++r)
                wreg[r] = *(const float4*)(wn + (size_t)r * JK);
        }

        // --- fragments + MFMA ---
        const int mrow = lane & 15;
        const int q    = lane >> 4;
        #pragma unroll
        for (int h = 0; h < 2; ++h) {
            bf16x8 a[4], b[4];
            #pragma unroll
            for (int rt = 0; rt < 4; ++rt) {
                int rl   = wave * 64 + rt * 16 + mrow;
                int slot = (h * 4 + q) ^ (rl & 7);
                a[rt] = *reinterpret_cast<const bf16x8*>(&xs[rl * BK + slot * 8]);
            }
            #pragma unroll
            for (int ct = 0; ct < 4; ++ct) {
                int col = ct * 16 + mrow;
                b[ct] = *reinterpret_cast<const bf16x8*>(&wt[col * WSTRIDE + (h * 4 + q) * 8]);
            }
            #pragma unroll
            for (int rt = 0; rt < 4; ++rt)
                #pragma unroll
                for (int ct = 0; ct < 4; ++ct)
                    acc[rt][ct] = __builtin_amdgcn_mfma_f32_16x16x32_bf16(a[rt], b[ct], acc[rt][ct], 0, 0, 0);
        }
    }

    // --- epilogue: bf16 stores to this slab. D: col=lane&15, row=(lane>>4)*4+reg ---
    const int qe = lane >> 4;
    const int cl = lane & 15;
    u16* sp = slabs + (size_t)s * N_ROWS * JK;
    #pragma unroll
    for (int rt = 0; rt < 4; ++rt)
        #pragma unroll
        for (int ct = 0; ct < 4; ++ct)
            #pragma unroll
            for (int r = 0; r < 4; ++r) {
                int row = wave * 64 + rt * 16 + qe * 4 + r;
                int col = c0 + ct * 16 + cl;
                sp[(size_t)row * JK + col] = f2bf(acc[rt][ct][r]);
            }
}

// Kernel C: feats[n,jk] = sum_s slab[s][n,jk] (bf16 -> fp32).
__global__ __launch_bounds__(256) void reduce_kernel(const u16* __restrict__ slabs,
                                                     float* __restrict__ feats, int S)
{
    int t = blockIdx.x * 256 + threadIdx.x;      // 65536 threads x 8 elems
    float acc[8] = {};
    for (int s = 0; s < S; ++s) {
        uint4 v = *(const uint4*)(slabs + (size_t)s * N_ROWS * JK + (size_t)t * 8);
        const u16* h = (const u16*)&v;
        #pragma unroll
        for (int e = 0; e < 8; ++e) acc[e] += bf2f(h[e]);
    }
    float4* fp = (float4*)(feats + (size_t)t * 8);
    fp[0] = make_float4(acc[0], acc[1], acc[2], acc[3]);
    fp[1] = make_float4(acc[4], acc[5], acc[6], acc[7]);
}

// Kernel D: diversity[n,j] = sum_m exp(-sum_k |feats[n,j,k]-feats[m,j,k]|), m-chunked.
__global__ __launch_bounds__(256) void pairwise_kernel(const float* __restrict__ feats,
                                                       float* __restrict__ out)
{
    const int j = blockIdx.x;              // 0..127
    const int mq = blockIdx.y;             // 0..3 -> m chunk of 64
    const int n = threadIdx.x;

    __shared__ float F[N_ROWS * KDIM];     // 16 KB
    const float* fr = feats + (size_t)n * JK + j * KDIM;
    float4 v0 = ((const float4*)fr)[0];
    float4 v1 = ((const float4*)fr)[1];
    float4 v2 = ((const float4*)fr)[2];
    float4 v3 = ((const float4*)fr)[3];
    float4* Fp = (float4*)&F[n * KDIM];
    Fp[0] = v0; Fp[1] = v1; Fp[2] = v2; Fp[3] = v3;
    __syncthreads();

    float f[16] = { v0.x, v0.y, v0.z, v0.w, v1.x, v1.y, v1.z, v1.w,
                    v2.x, v2.y, v2.z, v2.w, v3.x, v3.y, v3.z, v3.w };
    float accum = 0.f;
    const int m0 = mq * 64;
    for (int m = 0; m < 64; ++m) {
        const float* Fm = &F[(m0 + m) * KDIM];   // wave-uniform -> LDS broadcast
        float l1 = 0.f;
        #pragma unroll
        for (int k = 0; k < 16; ++k) l1 += fabsf(f[k] - Fm[k]);
        accum += exp2f(-1.4426950408889634f * l1);
    }
    atomicAdd(&out[(size_t)n * OUT_F + IN_F + j], accum);
}

extern "C" void kernel_launch(void* const* d_in, const int* in_sizes, int n_in,
                              void* d_out, int out_size, void* d_ws, size_t ws_size,
                              hipStream_t stream)
{
    const float* X = (const float*)d_in[0];   // [256, 8192] fp32
    const float* T = (const float*)d_in[1];   // [8192, 128, 16] fp32 = [8192, 2048]
    float* out = (float*)d_out;               // [256, 8320] fp32

    float* feats = (float*)d_ws;                            // 2 MB fp32 [256,2048]
    u16*   Xb    = (u16*)((char*)d_ws + (2u << 20));        // 4 MB bf16 [256,8192]
    u16*   slabs = (u16*)((char*)d_ws + (6u << 20));        // S MB bf16 [S,256,2048]

    int S = 16;                                             // split-K factor
    if (ws_size < (6u << 20) + (size_t)16 * N_ROWS * JK * 2) S = 8;
    if (ws_size < (6u << 20) + (size_t)8  * N_ROWS * JK * 2) S = 4;
    int kchunk = IN_F / S;

    prep_kernel<<<2048, 256, 0, stream>>>(X, out, Xb);
    gemm_kernel<<<dim3(JK / BN, S), 256, 0, stream>>>(Xb, T, slabs, kchunk);
    reduce_kernel<<<256, 256, 0, stream>>>(slabs, feats, S);
    pairwise_kernel<<<dim3(JDIM, 4), 256, 0, stream>>>(feats, out);
}